// Round 7
// baseline (168.757 us; speedup 1.0000x reference)
//
#include <hip/hip_runtime.h>
#include <hip/hip_fp16.h>

#define FSIZE   768
#define TW0     769
#define TW1     193
#define COL1    576
#define NPAIRS  300000
#define NCODES  30000
#define NROWS   8192
#define W1STRIDE 200
#define NCB     32768

// tier A2 (new): task0 = 32 pairs/wave, XCD code-partitioned
#define NWAVES0 (NPAIRS / 32)               // 9375
#define NB0     ((NWAVES0 + 3) / 4)         // 2344 (divisible by 8)
#define NB0Q    (NB0 / 8)                   // 293
#define NB1     (NPAIRS / 32)               // 9375
#define NPART   (NB0 + NB1)                 // 11719

// tier B (R6 structure): task0 = 16 pairs/wave
#define NWAVES0B (NPAIRS / 16)              // 18750
#define NB0B    ((NWAVES0B + 3) / 4)        // 4688
#define NPARTB  (NB0B + NB1)

#define SZ_FEAT16 (NROWS * FSIZE / 2)       // 4B units
#define SZ_W016   (NCODES * FSIZE / 2)
#define SZ_W116   (NCODES * W1STRIDE / 2)

typedef _Float16 h2_t __attribute__((ext_vector_type(2)));

#if defined(__has_builtin)
# if __has_builtin(__builtin_amdgcn_fdot2)
#  define HAVE_FDOT2 1
# endif
#endif

__device__ __forceinline__ float fdot2f(h2_t a, h2_t b, float c) {
#ifdef HAVE_FDOT2
    return __builtin_amdgcn_fdot2(a, b, c, false);
#else
    return (float)a[0] * (float)b[0] + (float)a[1] * (float)b[1] + c;
#endif
}

__device__ __forceinline__ float loss_term(float x, float y) {
    float ax = fabsf(x);
    return fmaxf(x, 0.0f) + log1pf(__expf(-ax)) - x * y;
}

__device__ __forceinline__ float4 ld4u(const float* p) {
    float4 v; __builtin_memcpy(&v, p, 16); return v;
}

__device__ __forceinline__ float acc8(uint4 u, float4 wa, float4 wb, float s) {
    h2_t h0, h1, h2v, h3;
    __builtin_memcpy(&h0, &u.x, 4);
    __builtin_memcpy(&h1, &u.y, 4);
    __builtin_memcpy(&h2v, &u.z, 4);
    __builtin_memcpy(&h3, &u.w, 4);
    s += (float)h0[0] * wa.x; s += (float)h0[1] * wa.y;
    s += (float)h1[0] * wa.z; s += (float)h1[1] * wa.w;
    s += (float)h2v[0] * wb.x; s += (float)h2v[1] * wb.y;
    s += (float)h3[0] * wb.z; s += (float)h3[1] * wb.w;
    return s;
}

__device__ __forceinline__ float dot8hh(uint4 a, uint4 b, float s) {
    h2_t a0, a1, a2, a3, b0, b1, b2, b3;
    __builtin_memcpy(&a0, &a.x, 4); __builtin_memcpy(&a1, &a.y, 4);
    __builtin_memcpy(&a2, &a.z, 4); __builtin_memcpy(&a3, &a.w, 4);
    __builtin_memcpy(&b0, &b.x, 4); __builtin_memcpy(&b1, &b.y, 4);
    __builtin_memcpy(&b2, &b.z, 4); __builtin_memcpy(&b3, &b.w, 4);
    s = fdot2f(a0, b0, s); s = fdot2f(a1, b1, s);
    s = fdot2f(a2, b2, s); s = fdot2f(a3, b3, s);
    return s;
}

// K1: feat f32 -> fp16, fused with histogram zeroing
__global__ __launch_bounds__(256) void conv_feat_kernel(
    const float* __restrict__ in, __half* __restrict__ out, int* __restrict__ cnt)
{
    const int gid = blockIdx.x * 256 + threadIdx.x;
    const int i = gid * 4;
    if (i < NROWS * FSIZE) {
        float4 v = *(const float4*)(in + i);
        __half2* o = (__half2*)(out + i);
        o[0] = __floats2half2_rn(v.x, v.y);
        o[1] = __floats2half2_rn(v.z, v.w);
    }
    if (gid < NCB) cnt[gid] = 0;
}

// K2 (tier A2): w0 f32 -> fp16 (stride 768, bias split out) + idx0 histogram
__global__ __launch_bounds__(256) void conv_w0_hist_kernel(
    const float* __restrict__ w0, __half* __restrict__ w016,
    float* __restrict__ b0f, const int* __restrict__ idx0, int* __restrict__ cnt)
{
    const int gid = blockIdx.x * 256 + threadIdx.x;   // 8 floats per thread
    if (gid < NCODES * (FSIZE / 8)) {
        const int c = gid / (FSIZE / 8);
        const int e = (gid - c * (FSIZE / 8)) * 8;
        const float* src = w0 + (size_t)c * TW0 + e;
        float4 a = ld4u(src), b = ld4u(src + 4);
        __half2* dst = (__half2*)(w016 + (size_t)c * FSIZE + e);
        dst[0] = __floats2half2_rn(a.x, a.y);
        dst[1] = __floats2half2_rn(a.z, a.w);
        dst[2] = __floats2half2_rn(b.x, b.y);
        dst[3] = __floats2half2_rn(b.z, b.w);
        if (e == 0) b0f[c] = w0[(size_t)c * TW0 + FSIZE];
    }
    if (gid < NPAIRS) atomicAdd(&cnt[idx0[2 * gid + 1]], 1);
}

// K2b (tier A2): w1 f32 -> fp16 (stride 200)
__global__ __launch_bounds__(256) void conv_w1_kernel(
    const float* __restrict__ w1, __half* __restrict__ out)
{
    const int gid = blockIdx.x * 256 + threadIdx.x;
    const int i4 = gid * 4;
    if (i4 < NCODES * W1STRIDE) {
        const int c = i4 / W1STRIDE;
        const int e = i4 - c * W1STRIDE;
        const float* src = w1 + (size_t)c * TW1;
        float v0 = 0.f, v1 = 0.f, v2 = 0.f, v3 = 0.f;
        if (e + 3 < TW1) {
            float4 f = ld4u(src + e);
            v0 = f.x; v1 = f.y; v2 = f.z; v3 = f.w;
        } else {
            if (e     < TW1) v0 = src[e];
            if (e + 1 < TW1) v1 = src[e + 1];
            if (e + 2 < TW1) v2 = src[e + 2];
        }
        __half2* dst = (__half2*)(out + i4);
        dst[0] = __floats2half2_rn(v0, v1);
        dst[1] = __floats2half2_rn(v2, v3);
    }
}

// K2 (tier B): w1 conv + hist (R6 behavior)
__global__ __launch_bounds__(256) void conv_w1_hist_kernel(
    const float* __restrict__ w1, __half* __restrict__ out,
    const int* __restrict__ idx0, int* __restrict__ cnt)
{
    const int gid = blockIdx.x * 256 + threadIdx.x;
    const int i4 = gid * 4;
    if (i4 < NCODES * W1STRIDE) {
        const int c = i4 / W1STRIDE;
        const int e = i4 - c * W1STRIDE;
        const float* src = w1 + (size_t)c * TW1;
        float v0 = 0.f, v1 = 0.f, v2 = 0.f, v3 = 0.f;
        if (e + 3 < TW1) {
            float4 f = ld4u(src + e);
            v0 = f.x; v1 = f.y; v2 = f.z; v3 = f.w;
        } else {
            if (e     < TW1) v0 = src[e];
            if (e + 1 < TW1) v1 = src[e + 1];
            if (e + 2 < TW1) v2 = src[e + 2];
        }
        __half2* dst = (__half2*)(out + i4);
        dst[0] = __floats2half2_rn(v0, v1);
        dst[1] = __floats2half2_rn(v2, v3);
    }
    if (gid < NPAIRS) atomicAdd(&cnt[idx0[2 * gid + 1]], 1);
}

__global__ __launch_bounds__(256) void hist_kernel(const int* __restrict__ idx,
                                                   int* __restrict__ cnt) {
    int p = blockIdx.x * 256 + threadIdx.x;
    if (p < NPAIRS) atomicAdd(&cnt[idx[2 * p + 1]], 1);
}

// K3: exclusive scan of 32768 bins — shfl-based
__global__ __launch_bounds__(1024) void scan_kernel(const int* __restrict__ cnt,
                                                    int* __restrict__ cursor) {
    __shared__ int wsum[16];
    __shared__ int wbase[16];
    const int t = threadIdx.x;
    const int lane = t & 63, wv = t >> 6;
    const int4* c4 = (const int4*)cnt + t * 8;
    int4 v[8];
#pragma unroll
    for (int j = 0; j < 8; ++j) v[j] = c4[j];
    int loc[32];
    int s = 0;
#pragma unroll
    for (int j = 0; j < 8; ++j) {
        loc[4 * j + 0] = s; s += v[j].x;
        loc[4 * j + 1] = s; s += v[j].y;
        loc[4 * j + 2] = s; s += v[j].z;
        loc[4 * j + 3] = s; s += v[j].w;
    }
    int incl = s;
#pragma unroll
    for (int off = 1; off < 64; off <<= 1) {
        int u = __shfl_up(incl, off, 64);
        if (lane >= off) incl += u;
    }
    if (lane == 63) wsum[wv] = incl;
    __syncthreads();
    if (wv == 0 && lane < 16) {
        int mysum = wsum[lane];
        int winc = mysum;
#pragma unroll
        for (int off = 1; off < 16; off <<= 1) {
            int u = __shfl_up(winc, off, 64);
            if (lane >= off) winc += u;
        }
        wbase[lane] = winc - mysum;
    }
    __syncthreads();
    const int base = wbase[wv] + incl - s;
    int4* cu = (int4*)cursor + t * 8;
#pragma unroll
    for (int j = 0; j < 8; ++j)
        cu[j] = make_int4(base + loc[4 * j], base + loc[4 * j + 1],
                          base + loc[4 * j + 2], base + loc[4 * j + 3]);
}

// K4: scatter packed records {r, c, y_bits, p}
__global__ __launch_bounds__(256) void scatter_kernel(
    const int* __restrict__ idx, const float* __restrict__ y,
    int* __restrict__ cursor, uint4* __restrict__ srec)
{
    int p = blockIdx.x * 256 + threadIdx.x;
    if (p < NPAIRS) {
        int r = idx[2 * p];
        int c = idx[2 * p + 1];
        int pos = atomicAdd(&cursor[c], 1);
        srec[pos] = make_uint4((unsigned)r, (unsigned)c, __float_as_uint(y[p]), (unsigned)p);
    }
}

// K5 (tier A2): task0 — 16-lane groups, 8-pair spans, fp16 w0 reg-cached,
// XCD-partitioned by code range via bijective block swizzle.
//               task1 — 8-lane groups, fp16 both sides.
__global__ __launch_bounds__(256) void main2_kernel(
    const __half* __restrict__ feat16, const __half* __restrict__ w016,
    const float* __restrict__ b0f, const __half* __restrict__ w116,
    const uint4* __restrict__ srec,
    const int* __restrict__ idx1, const float* __restrict__ y1,
    float* __restrict__ out_final, float* __restrict__ partial)
{
    __shared__ float bsum[4];
    const int lane = threadIdx.x & 63;
    const int wv   = threadIdx.x >> 6;
    float wavesum = 0.f;

    if (blockIdx.x < NB0) {
        // XCD k (≈ bid%8) gets contiguous sorted-pair (= code) range
        const int work = (blockIdx.x & 7) * NB0Q + (blockIdx.x >> 3);
        const int wid = work * 4 + wv;
        if (wid < NWAVES0) {
            const int g = lane >> 4, sub = lane & 15;
            const uint4 rec = srec[wid * 32 + 8 * g + (sub & 7)];
            int prev_c = -1;
            uint4 wc[6];
            float wb = 0.f, lg = 0.f;
#pragma unroll
            for (int j = 0; j < 8; ++j) {
                const int src = (lane & 48) | j;
                const int r = __shfl((int)rec.x, src, 64);
                const int c = __shfl((int)rec.y, src, 64);
                if (c != prev_c) {                  // group-uniform
                    prev_c = c;
                    const __half* wrow = w016 + (size_t)c * FSIZE + 8 * sub;
#pragma unroll
                    for (int k = 0; k < 6; ++k)
                        wc[k] = *(const uint4*)(wrow + 128 * k);
                    wb = b0f[c];
                }
                const __half* fr = feat16 + (size_t)r * FSIZE + 8 * sub;
                float s = 0.f;
#pragma unroll
                for (int k = 0; k < 6; ++k) {
                    uint4 u = *(const uint4*)(fr + 128 * k);
                    s = dot8hh(u, wc[k], s);
                }
                s += __shfl_xor(s, 8, 64);
                s += __shfl_xor(s, 4, 64);
                s += __shfl_xor(s, 2, 64);
                s += __shfl_xor(s, 1, 64);
                s += wb;
                lg = (sub == j) ? s : lg;           // pair 8g+j parks in lane (g,j)
            }
            float ll = 0.f;
            if (sub < 8) {
                out_final[rec.w] = lg;
                ll = loss_term(lg, __uint_as_float(rec.z));
            }
#pragma unroll
            for (int m = 32; m; m >>= 1) ll += __shfl_xor(ll, m, 64);
            wavesum = ll;
        }
    } else {
        const int bid  = blockIdx.x - NB0;
        const int sub  = lane & 7;
        const int pair = (bid * 4 + wv) * 8 + (lane >> 3);
        const int r = idx1[2 * pair];
        const int c = idx1[2 * pair + 1];
        const __half* fr = feat16 + (size_t)r * FSIZE + COL1 + 8 * sub;
        const __half* wr = w116 + (size_t)c * W1STRIDE + 8 * sub;
        float s = 0.f;
#pragma unroll
        for (int k = 0; k < 3; ++k) {
            uint4 uf = *(const uint4*)(fr + 64 * k);
            uint4 uw = *(const uint4*)(wr + 64 * k);
            s = dot8hh(uf, uw, s);
        }
        float bias = __half2float(w116[(size_t)c * W1STRIDE + 192]);
        s += __shfl_xor(s, 4, 64);
        s += __shfl_xor(s, 2, 64);
        s += __shfl_xor(s, 1, 64);
        float ll = (sub == 0) ? loss_term(s + bias, y1[pair]) : 0.f;
#pragma unroll
        for (int m = 32; m; m >>= 1) ll += __shfl_xor(ll, m, 64);
        wavesum = ll;
    }

    if (lane == 0) bsum[wv] = wavesum;
    __syncthreads();
    if (threadIdx.x == 0)
        partial[blockIdx.x] = bsum[0] + bsum[1] + bsum[2] + bsum[3];
}

// K5 (tier B): R6 main kernel (f32 w0 reg-cached, 4-pair spans)
template <bool W1H>
__global__ __launch_bounds__(256, 4) void main_kernel(
    const __half* __restrict__ feat16, const float* __restrict__ w0,
    const float* __restrict__ w1f, const __half* __restrict__ w116,
    const uint4* __restrict__ srec,
    const int* __restrict__ idx1, const float* __restrict__ y1,
    float* __restrict__ out_final, float* __restrict__ partial)
{
    __shared__ float bsum[4];
    const int lane = threadIdx.x & 63;
    const int wv   = threadIdx.x >> 6;
    float wavesum = 0.f;

    if (blockIdx.x < NB0B) {
        const int wid = blockIdx.x * 4 + wv;
        if (wid < NWAVES0B) {
            const int g = lane >> 4, sub = lane & 15;
            const uint4 rec = srec[wid * 16 + 4 * g + (sub & 3)];
            int prev_c = -1;
            float4 wc[12];
            float wb = 0.f;
            float lg = 0.f;
#pragma unroll
            for (int j = 0; j < 4; ++j) {
                const int src = (lane & 48) | j;
                const int r = __shfl((int)rec.x, src, 64);
                const int c = __shfl((int)rec.y, src, 64);
                if (c != prev_c) {
                    prev_c = c;
                    const float* wrow = w0 + (size_t)c * TW0 + 8 * sub;
#pragma unroll
                    for (int k = 0; k < 6; ++k) {
                        wc[2 * k]     = ld4u(wrow + 128 * k);
                        wc[2 * k + 1] = ld4u(wrow + 128 * k + 4);
                    }
                    wb = w0[(size_t)c * TW0 + FSIZE];
                }
                const __half* fr = feat16 + (size_t)r * FSIZE + 8 * sub;
                float s = 0.f;
#pragma unroll
                for (int k = 0; k < 6; ++k) {
                    uint4 u = *(const uint4*)(fr + 128 * k);
                    s = acc8(u, wc[2 * k], wc[2 * k + 1], s);
                }
                s += __shfl_xor(s, 8, 64);
                s += __shfl_xor(s, 4, 64);
                s += __shfl_xor(s, 2, 64);
                s += __shfl_xor(s, 1, 64);
                s += wb;
                lg = (sub == j) ? s : lg;
            }
            float ll = 0.f;
            if (sub < 4) {
                out_final[rec.w] = lg;
                ll = loss_term(lg, __uint_as_float(rec.z));
            }
#pragma unroll
            for (int m = 32; m; m >>= 1) ll += __shfl_xor(ll, m, 64);
            wavesum = ll;
        }
    } else {
        const int bid  = blockIdx.x - NB0B;
        const int sub  = lane & 7;
        const int pair = (bid * 4 + wv) * 8 + (lane >> 3);
        const int r = idx1[2 * pair];
        const int c = idx1[2 * pair + 1];
        const __half* fr = feat16 + (size_t)r * FSIZE + COL1 + 8 * sub;
        float s = 0.f;
        float bias;
        if (W1H) {
            const __half* wr = w116 + (size_t)c * W1STRIDE + 8 * sub;
#pragma unroll
            for (int k = 0; k < 3; ++k) {
                uint4 uf = *(const uint4*)(fr + 64 * k);
                uint4 uw = *(const uint4*)(wr + 64 * k);
                s = dot8hh(uf, uw, s);
            }
            bias = __half2float(w116[(size_t)c * W1STRIDE + 192]);
        } else {
            const float* wr = w1f + (size_t)c * TW1 + 8 * sub;
#pragma unroll
            for (int k = 0; k < 3; ++k) {
                uint4 uf = *(const uint4*)(fr + 64 * k);
                s = acc8(uf, ld4u(wr + 64 * k), ld4u(wr + 64 * k + 4), s);
            }
            bias = w1f[(size_t)c * TW1 + 192];
        }
        s += __shfl_xor(s, 4, 64);
        s += __shfl_xor(s, 2, 64);
        s += __shfl_xor(s, 1, 64);
        float ll = (sub == 0) ? loss_term(s + bias, y1[pair]) : 0.f;
#pragma unroll
        for (int m = 32; m; m >>= 1) ll += __shfl_xor(ll, m, 64);
        wavesum = ll;
    }

    if (lane == 0) bsum[wv] = wavesum;
    __syncthreads();
    if (threadIdx.x == 0)
        partial[blockIdx.x] = bsum[0] + bsum[1] + bsum[2] + bsum[3];
}

__global__ __launch_bounds__(1024) void reduce_kernel(
    const float* __restrict__ partial, int n, float* __restrict__ out)
{
    __shared__ float sh[1024];
    float s = 0.0f;
    for (int i = threadIdx.x; i < n; i += 1024) s += partial[i];
    sh[threadIdx.x] = s;
    __syncthreads();
    for (int off = 512; off; off >>= 1) {
        if ((int)threadIdx.x < off) sh[threadIdx.x] += sh[threadIdx.x + off];
        __syncthreads();
    }
    if (threadIdx.x == 0) out[0] = sh[0];
}

// ---------------- tier C fallback (all-f32, unsorted) ----------------
__global__ __launch_bounds__(256) void task0_kernel(
    const float* __restrict__ feat, const float* __restrict__ wt,
    const int* __restrict__ idx, const float* __restrict__ y,
    float* __restrict__ out_final, float* __restrict__ partial)
{
    __shared__ float lsum[4];
    const int lane = threadIdx.x & 63;
    const int wv = threadIdx.x >> 6;
    const int pair = blockIdx.x * 4 + wv;
    const int r = idx[2 * pair];
    const int c = idx[2 * pair + 1];
    const float4* f4 = (const float4*)(feat + (size_t)r * FSIZE);
    const float* wrow = wt + (size_t)c * TW0;
    float s = 0.0f;
#pragma unroll
    for (int k = 0; k < 3; ++k) {
        const int j = lane + (k << 6);
        float4 f = f4[j];
        float4 w = ld4u(wrow + 4 * j);
        s += f.x * w.x + f.y * w.y + f.z * w.z + f.w * w.w;
    }
#pragma unroll
    for (int m = 32; m; m >>= 1) s += __shfl_xor(s, m, 64);
    if (lane == 0) {
        const float logit = s + wrow[FSIZE];
        out_final[pair] = logit;
        lsum[wv] = loss_term(logit, y[pair]);
    }
    __syncthreads();
    if (threadIdx.x == 0)
        partial[blockIdx.x] = lsum[0] + lsum[1] + lsum[2] + lsum[3];
}

__global__ __launch_bounds__(256) void task1_kernel(
    const float* __restrict__ feat, const float* __restrict__ wt,
    const int* __restrict__ idx, const float* __restrict__ y,
    float* __restrict__ partial)
{
    __shared__ float lsum[16];
    const int lane = threadIdx.x & 63;
    const int wv = threadIdx.x >> 6;
    const int sub = lane & 15;
    const int pg = lane >> 4;
    const int pair = (blockIdx.x * 4 + wv) * 4 + pg;
    const int r = idx[2 * pair];
    const int c = idx[2 * pair + 1];
    const float4* f4 = (const float4*)(feat + (size_t)r * FSIZE + COL1);
    const float* wrow = wt + (size_t)c * TW1;
    float s = 0.0f;
#pragma unroll
    for (int k = 0; k < 3; ++k) {
        const int j = sub + (k << 4);
        float4 f = f4[j];
        float4 w = ld4u(wrow + 4 * j);
        s += f.x * w.x + f.y * w.y + f.z * w.z + f.w * w.w;
    }
#pragma unroll
    for (int m = 8; m; m >>= 1) s += __shfl_xor(s, m, 64);
    if (sub == 0) {
        const float logit = s + wrow[TW1 - 1];
        lsum[wv * 4 + pg] = loss_term(logit, y[pair]);
    }
    __syncthreads();
    if (threadIdx.x == 0) {
        float t = 0.0f;
#pragma unroll
        for (int i = 0; i < 16; ++i) t += lsum[i];
        partial[blockIdx.x] = t;
    }
}

extern "C" void kernel_launch(void* const* d_in, const int* in_sizes, int n_in,
                              void* d_out, int out_size, void* d_ws, size_t ws_size,
                              hipStream_t stream) {
    const float* feat = (const float*)d_in[0];
    const float* w0   = (const float*)d_in[1];
    const float* w1   = (const float*)d_in[2];
    const int*   idx0 = (const int*)d_in[3];
    const float* y0   = (const float*)d_in[4];
    const int*   idx1 = (const int*)d_in[6];
    const float* y1   = (const float*)d_in[7];

    float* out = (float*)d_out;
    float* ws  = (float*)d_ws;

    const size_t commonU = (size_t)NCB * 2 + (size_t)NPAIRS * 4 + 64;
    const size_t needA2 = (SZ_FEAT16 + SZ_W016 + SZ_W116 + NCODES + commonU + NPART) * 4;
    const size_t needB  = (SZ_FEAT16 + SZ_W116 + commonU + NPARTB) * 4;
    const size_t needB2 = (SZ_FEAT16 + commonU + NPARTB) * 4;

    if (ws_size >= needA2) {
        size_t off = 0;
        __half* feat16 = (__half*)(ws + off); off += SZ_FEAT16;
        __half* w016   = (__half*)(ws + off); off += SZ_W016;
        __half* w116   = (__half*)(ws + off); off += SZ_W116;
        float*  b0f    = ws + off;            off += NCODES;
        int* cnt       = (int*)(ws + off);    off += NCB;
        int* cursor    = (int*)(ws + off);    off += NCB;
        uint4* srec    = (uint4*)(ws + off);  off += (size_t)NPAIRS * 4;
        float* part    = ws + off;

        conv_feat_kernel<<<NROWS * FSIZE / 4 / 256, 256, 0, stream>>>(feat, feat16, cnt);
        conv_w0_hist_kernel<<<(NCODES * (FSIZE / 8) + 255) / 256, 256, 0, stream>>>(
            w0, w016, b0f, idx0, cnt);
        conv_w1_kernel<<<(NCODES * W1STRIDE / 4 + 255) / 256, 256, 0, stream>>>(w1, w116);
        scan_kernel<<<1, 1024, 0, stream>>>(cnt, cursor);
        scatter_kernel<<<(NPAIRS + 255) / 256, 256, 0, stream>>>(idx0, y0, cursor, srec);
        main2_kernel<<<NB0 + NB1, 256, 0, stream>>>(
            feat16, w016, b0f, w116, srec, idx1, y1, out, part);
        reduce_kernel<<<1, 1024, 0, stream>>>(part, NPART, out + NPAIRS);
    } else if (ws_size >= needB2) {
        const bool tierB = (ws_size >= needB);
        size_t off = 0;
        __half* feat16 = (__half*)(ws + off); off += SZ_FEAT16;
        __half* w116 = nullptr;
        if (tierB) { w116 = (__half*)(ws + off); off += SZ_W116; }
        int* cnt    = (int*)(ws + off); off += NCB;
        int* cursor = (int*)(ws + off); off += NCB;
        uint4* srec = (uint4*)(ws + off); off += (size_t)NPAIRS * 4;
        float* part = ws + off;

        conv_feat_kernel<<<NROWS * FSIZE / 4 / 256, 256, 0, stream>>>(feat, feat16, cnt);
        if (tierB)
            conv_w1_hist_kernel<<<(NCODES * W1STRIDE / 4 + 255) / 256, 256, 0, stream>>>(
                w1, w116, idx0, cnt);
        else
            hist_kernel<<<(NPAIRS + 255) / 256, 256, 0, stream>>>(idx0, cnt);
        scan_kernel<<<1, 1024, 0, stream>>>(cnt, cursor);
        scatter_kernel<<<(NPAIRS + 255) / 256, 256, 0, stream>>>(idx0, y0, cursor, srec);
        if (tierB)
            main_kernel<true><<<NB0B + NB1, 256, 0, stream>>>(
                feat16, w0, w1, w116, srec, idx1, y1, out, part);
        else
            main_kernel<false><<<NB0B + NB1, 256, 0, stream>>>(
                feat16, w0, w1, nullptr, srec, idx1, y1, out, part);
        reduce_kernel<<<1, 1024, 0, stream>>>(part, NPARTB, out + NPAIRS);
    } else {
        float* part = ws;
        const int nb0 = NPAIRS / 4;
        const int nb1 = NPAIRS / 16;
        task0_kernel<<<nb0, 256, 0, stream>>>(feat, w0, idx0, y0, out, part);
        task1_kernel<<<nb1, 256, 0, stream>>>(feat, w1, idx1, y1, part + nb0);
        reduce_kernel<<<1, 1024, 0, stream>>>(part, nb0 + nb1, out + NPAIRS);
    }
}

// Round 10
// 161.275 us; speedup vs baseline: 1.0464x; 1.0464x over previous
//
#include <hip/hip_runtime.h>
#include <hip/hip_fp16.h>

#define FSIZE   768
#define TW0     769
#define TW1     193
#define COL1    576
#define NPAIRS  300000
#define NCODES  30000
#define NROWS   8192
#define NCB     32768

// main grid
#define NWAVES0 (NPAIRS / 32)               // 9375
#define NB0     2344                        // task0 blocks (div by 8)
#define NB1     1176                        // task1 blocks (div by 8), padded
#define NGRID   (NB0 + NB1)                 // 3520
#define NPART   NGRID

// fused pre-pass sections (blocks)
#define NBF     3072                        // feat conv: 8192*768/8/256
#define NBW0    11250                       // w0 conv:  30000*96/256
#define NBW1    2813                        // w1 conv:  ceil(30000*24/256)
#define NBH     2344                        // hist:     ceil(600000/256)
#define PRE_S1  (NBF)
#define PRE_S2  (NBF + NBW0)
#define PRE_S3  (NBF + NBW0 + NBW1)
#define NPRE    (NBF + NBW0 + NBW1 + NBH)

// ws layout in 4-byte units
#define O_FEAT8  ((size_t)0)
#define O_W08    (O_FEAT8 + 1572864)
#define O_W18    (O_W08 + 5760000)
#define O_B0F    (O_W18 + 1440000)
#define O_B1F    (O_B0F + 30000)
#define O_CNT    (O_B1F + 30000)
#define O_CUR    (O_CNT + 65536)
#define O_SREC   (O_CUR + 65536)
#define O_PART   (O_SREC + 2400000)
#define WS_U32   (O_PART + NPART + 64)

#define FSCALE   16.0f
#define WSCALE   64.0f
#define DESCALE  (1.0f / 1024.0f)

typedef float f32x2_t __attribute__((ext_vector_type(2)));

__device__ __forceinline__ float loss_term(float x, float y) {
    float ax = fabsf(x);
    return fmaxf(x, 0.0f) + log1pf(__expf(-ax)) - x * y;
}

__device__ __forceinline__ float4 ld4u(const float* p) {
    float4 v; __builtin_memcpy(&v, p, 16); return v;
}

#if defined(__has_builtin)
# if __has_builtin(__builtin_amdgcn_cvt_pk_f32_fp8)
#  define HW_FP8_DEC 1
# endif
# if __has_builtin(__builtin_amdgcn_cvt_pk_fp8_f32)
#  define HW_FP8_ENC 1
# endif
#endif

__device__ __forceinline__ float sw_fp8_to_f32(unsigned b) {
    unsigned mag = b & 0x7fu;
    unsigned r = ((b & 0x80u) << 24) | ((mag << 20) + 0x3C000000u);
    float f = __uint_as_float(r);
    return mag ? f : 0.0f;
}

template <bool HI>
__device__ __forceinline__ f32x2_t fp8x2_to_f32(unsigned u) {
#ifdef HW_FP8_DEC
    return __builtin_amdgcn_cvt_pk_f32_fp8(u, HI);   // native v2f32, HI is constexpr
#else
    f32x2_t o;
    unsigned lo8 = HI ? ((u >> 16) & 0xffu) : (u & 0xffu);
    unsigned hi8 = HI ? ((u >> 24) & 0xffu) : ((u >> 8) & 0xffu);
    o[0] = sw_fp8_to_f32(lo8);
    o[1] = sw_fp8_to_f32(hi8);
    return o;
#endif
}

__device__ __forceinline__ unsigned sw_f32_to_fp8(float x) {
    unsigned short h = __half_as_ushort(__float2half(x));
    unsigned s = ((unsigned)h >> 8) & 0x80u;
    int e = (h >> 10) & 31;
    unsigned m = h & 1023u;
    if (e >= 23) return s | 0x7eu;            // sat to 448 (also inf/nan)
    if (e < 9)  return s;                     // flush tiny (scaled data: rare)
    unsigned t = ((unsigned)(e - 8) << 3) | (m >> 7);
    unsigned rnd = (m >> 6) & 1u, sticky = (m & 63u) ? 1u : 0u;
    t += (rnd & (sticky | (t & 1u)));
    if (t > 0x7eu) t = 0x7eu;
    return s | t;
}

__device__ __forceinline__ unsigned f32x4_to_fp8(float a, float b, float c, float d) {
#ifdef HW_FP8_ENC
    int u = __builtin_amdgcn_cvt_pk_fp8_f32(a, b, 0, false);
    u = __builtin_amdgcn_cvt_pk_fp8_f32(c, d, u, true);
    return (unsigned)u;
#else
    return sw_f32_to_fp8(a) | (sw_f32_to_fp8(b) << 8)
         | (sw_f32_to_fp8(c) << 16) | (sw_f32_to_fp8(d) << 24);
#endif
}

// 16 fp8 (uint4) dotted against 16 cached f32 weights
__device__ __forceinline__ float dot16(uint4 u, const float* w, float s) {
    f32x2_t p;
    p = fp8x2_to_f32<false>(u.x); s += p[0] * w[0]  + p[1] * w[1];
    p = fp8x2_to_f32<true >(u.x); s += p[0] * w[2]  + p[1] * w[3];
    p = fp8x2_to_f32<false>(u.y); s += p[0] * w[4]  + p[1] * w[5];
    p = fp8x2_to_f32<true >(u.y); s += p[0] * w[6]  + p[1] * w[7];
    p = fp8x2_to_f32<false>(u.z); s += p[0] * w[8]  + p[1] * w[9];
    p = fp8x2_to_f32<true >(u.z); s += p[0] * w[10] + p[1] * w[11];
    p = fp8x2_to_f32<false>(u.w); s += p[0] * w[12] + p[1] * w[13];
    p = fp8x2_to_f32<true >(u.w); s += p[0] * w[14] + p[1] * w[15];
    return s;
}

__device__ __forceinline__ float dot8(uint2 u, const float* w, float s) {
    f32x2_t p;
    p = fp8x2_to_f32<false>(u.x); s += p[0] * w[0] + p[1] * w[1];
    p = fp8x2_to_f32<true >(u.x); s += p[0] * w[2] + p[1] * w[3];
    p = fp8x2_to_f32<false>(u.y); s += p[0] * w[4] + p[1] * w[5];
    p = fp8x2_to_f32<true >(u.y); s += p[0] * w[6] + p[1] * w[7];
    return s;
}

__device__ __forceinline__ void unpack16(uint4 u, float* w) {
    f32x2_t p;
    p = fp8x2_to_f32<false>(u.x); w[0]  = p[0]; w[1]  = p[1];
    p = fp8x2_to_f32<true >(u.x); w[2]  = p[0]; w[3]  = p[1];
    p = fp8x2_to_f32<false>(u.y); w[4]  = p[0]; w[5]  = p[1];
    p = fp8x2_to_f32<true >(u.y); w[6]  = p[0]; w[7]  = p[1];
    p = fp8x2_to_f32<false>(u.z); w[8]  = p[0]; w[9]  = p[1];
    p = fp8x2_to_f32<true >(u.z); w[10] = p[0]; w[11] = p[1];
    p = fp8x2_to_f32<false>(u.w); w[12] = p[0]; w[13] = p[1];
    p = fp8x2_to_f32<true >(u.w); w[14] = p[0]; w[15] = p[1];
}

__device__ __forceinline__ void unpack8(uint2 u, float* w) {
    f32x2_t p;
    p = fp8x2_to_f32<false>(u.x); w[0] = p[0]; w[1] = p[1];
    p = fp8x2_to_f32<true >(u.x); w[2] = p[0]; w[3] = p[1];
    p = fp8x2_to_f32<false>(u.y); w[4] = p[0]; w[5] = p[1];
    p = fp8x2_to_f32<true >(u.y); w[6] = p[0]; w[7] = p[1];
}

__global__ __launch_bounds__(256) void zero_cnt_kernel(int* __restrict__ cnt) {
    cnt[blockIdx.x * 256 + threadIdx.x] = 0;   // grid = 256 blocks == 65536 ints
}

// Fused pre-pass: feat->fp8 | w0->fp8+bias | w1->fp8+bias | both histograms
__global__ __launch_bounds__(256) void fused_pre_kernel(
    const float* __restrict__ feat, const float* __restrict__ w0,
    const float* __restrict__ w1,
    const int* __restrict__ idx0, const int* __restrict__ idx1,
    uint2* __restrict__ feat8, uint2* __restrict__ w08, uint2* __restrict__ w18,
    float* __restrict__ b0f, float* __restrict__ b1f, int* __restrict__ cnt)
{
    const int bid = blockIdx.x;
    if (bid < PRE_S1) {
        const int t = bid * 256 + threadIdx.x;          // [0, 786432)
        const float* src = feat + (size_t)t * 8;
        float4 a = *(const float4*)src, b = *(const float4*)(src + 4);
        uint2 o;
        o.x = f32x4_to_fp8(a.x * FSCALE, a.y * FSCALE, a.z * FSCALE, a.w * FSCALE);
        o.y = f32x4_to_fp8(b.x * FSCALE, b.y * FSCALE, b.z * FSCALE, b.w * FSCALE);
        feat8[t] = o;
    } else if (bid < PRE_S2) {
        const int t = (bid - PRE_S1) * 256 + threadIdx.x;   // [0, 2880000)
        const int c = t / 96;
        const int e = (t - c * 96) * 8;
        const float* src = w0 + (size_t)c * TW0 + e;
        float4 a = ld4u(src), b = ld4u(src + 4);
        uint2 o;
        o.x = f32x4_to_fp8(a.x * WSCALE, a.y * WSCALE, a.z * WSCALE, a.w * WSCALE);
        o.y = f32x4_to_fp8(b.x * WSCALE, b.y * WSCALE, b.z * WSCALE, b.w * WSCALE);
        w08[t] = o;
        if (e == 0) b0f[c] = w0[(size_t)c * TW0 + FSIZE];
    } else if (bid < PRE_S3) {
        const int t = (bid - PRE_S2) * 256 + threadIdx.x;
        if (t < NCODES * 24) {
            const int c = t / 24;
            const int e = (t - c * 24) * 8;
            const float* src = w1 + (size_t)c * TW1 + e;
            float4 a = ld4u(src), b = ld4u(src + 4);
            uint2 o;
            o.x = f32x4_to_fp8(a.x * WSCALE, a.y * WSCALE, a.z * WSCALE, a.w * WSCALE);
            o.y = f32x4_to_fp8(b.x * WSCALE, b.y * WSCALE, b.z * WSCALE, b.w * WSCALE);
            w18[t] = o;
            if (e == 0) b1f[c] = w1[(size_t)c * TW1 + (TW1 - 1)];
        }
    } else {
        const int t = (bid - PRE_S3) * 256 + threadIdx.x;
        if (t < 2 * NPAIRS) {
            if (t < NPAIRS) atomicAdd(&cnt[idx0[2 * t + 1]], 1);
            else            atomicAdd(&cnt[NCB + idx1[2 * (t - NPAIRS) + 1]], 1);
        }
    }
}

// Cumulative exclusive scan over 65536 bins (both tasks; task1 offsets land
// at [NPAIRS, 2*NPAIRS) automatically since cnt0 sums to NPAIRS).
__global__ __launch_bounds__(1024) void scan2_kernel(const int* __restrict__ cnt,
                                                     int* __restrict__ cursor) {
    __shared__ int wsum[16];
    __shared__ int wbase[16];
    const int t = threadIdx.x;
    const int lane = t & 63, wv = t >> 6;
    const int4* c4 = (const int4*)cnt + (size_t)t * 16;
    int4 v[16];
#pragma unroll
    for (int j = 0; j < 16; ++j) v[j] = c4[j];
    int s = 0;
#pragma unroll
    for (int j = 0; j < 16; ++j) {
        int a;
        a = v[j].x; v[j].x = s; s += a;
        a = v[j].y; v[j].y = s; s += a;
        a = v[j].z; v[j].z = s; s += a;
        a = v[j].w; v[j].w = s; s += a;
    }
    int incl = s;
#pragma unroll
    for (int off = 1; off < 64; off <<= 1) {
        int u = __shfl_up(incl, off, 64);
        if (lane >= off) incl += u;
    }
    if (lane == 63) wsum[wv] = incl;
    __syncthreads();
    if (wv == 0 && lane < 16) {
        int mysum = wsum[lane];
        int winc = mysum;
#pragma unroll
        for (int off = 1; off < 16; off <<= 1) {
            int u = __shfl_up(winc, off, 64);
            if (lane >= off) winc += u;
        }
        wbase[lane] = winc - mysum;
    }
    __syncthreads();
    const int base = wbase[wv] + incl - s;
    int4* cu = (int4*)cursor + (size_t)t * 16;
#pragma unroll
    for (int j = 0; j < 16; ++j)
        cu[j] = make_int4(base + v[j].x, base + v[j].y, base + v[j].z, base + v[j].w);
}

// Scatter both tasks into one 600k-record array {r, c, y_bits, p}
__global__ __launch_bounds__(256) void scatter2_kernel(
    const int* __restrict__ idx0, const float* __restrict__ y0,
    const int* __restrict__ idx1, const float* __restrict__ y1,
    int* __restrict__ cursor, uint4* __restrict__ srec)
{
    const int t = blockIdx.x * 256 + threadIdx.x;
    if (t < NPAIRS) {
        int r = idx0[2 * t], c = idx0[2 * t + 1];
        int pos = atomicAdd(&cursor[c], 1);
        srec[pos] = make_uint4((unsigned)r, (unsigned)c, __float_as_uint(y0[t]), (unsigned)t);
    } else if (t < 2 * NPAIRS) {
        int p = t - NPAIRS;
        int r = idx1[2 * p], c = idx1[2 * p + 1];
        int pos = atomicAdd(&cursor[NCB + c], 1);
        srec[pos] = make_uint4((unsigned)r, (unsigned)c, __float_as_uint(y1[p]), (unsigned)p);
    }
}

// Main: task0 blocks [0,NB0): 16-lane groups, 8-pair sorted spans, fp8 w
// unpacked to 48 f32 regs per code-run, XCD code-partitioned.
//       task1 blocks [NB0,NGRID): 8-lane groups, 8-pair sorted spans, fp8 w1.
__global__ __launch_bounds__(256) void main3_kernel(
    const unsigned char* __restrict__ feat8, const unsigned char* __restrict__ w08,
    const unsigned char* __restrict__ w18,
    const float* __restrict__ b0f, const float* __restrict__ b1f,
    const uint4* __restrict__ srec,
    float* __restrict__ out_final, float* __restrict__ partial)
{
    __shared__ float bsum[4];
    const int lane = threadIdx.x & 63;
    const int wv   = threadIdx.x >> 6;
    float wavesum = 0.f;

    if (blockIdx.x < NB0) {
        const int work = (blockIdx.x & 7) * (NB0 / 8) + (blockIdx.x >> 3);
        const int wid = work * 4 + wv;
        if (wid < NWAVES0) {
            const int g = lane >> 4, sub = lane & 15;
            const uint4 rec = srec[(size_t)wid * 32 + 8 * g + (sub & 7)];
            int prev_c = -1;
            float wc[48];
            float wb = 0.f, lg = 0.f;
#pragma unroll
            for (int j = 0; j < 8; ++j) {
                const int src = (lane & 48) | j;
                const int r = __shfl((int)rec.x, src, 64);
                const int c = __shfl((int)rec.y, src, 64);
                if (c != prev_c) {                       // group-uniform
                    prev_c = c;
                    const unsigned char* wr = w08 + (size_t)c * FSIZE + 48 * sub;
                    uint4 wu0 = *(const uint4*)wr;
                    uint4 wu1 = *(const uint4*)(wr + 16);
                    uint4 wu2 = *(const uint4*)(wr + 32);
                    unpack16(wu0, &wc[0]);
                    unpack16(wu1, &wc[16]);
                    unpack16(wu2, &wc[32]);
                    wb = b0f[c];
                }
                const unsigned char* fr = feat8 + (size_t)r * FSIZE + 48 * sub;
                uint4 f0 = *(const uint4*)fr;
                uint4 f1 = *(const uint4*)(fr + 16);
                uint4 f2 = *(const uint4*)(fr + 32);
                float s = dot16(f0, &wc[0], 0.f);
                s = dot16(f1, &wc[16], s);
                s = dot16(f2, &wc[32], s);
                s += __shfl_xor(s, 8, 64);
                s += __shfl_xor(s, 4, 64);
                s += __shfl_xor(s, 2, 64);
                s += __shfl_xor(s, 1, 64);
                lg = (sub == j) ? s * DESCALE + wb : lg;
            }
            float ll = 0.f;
            if (sub < 8) {
                out_final[rec.w] = lg;
                ll = loss_term(lg, __uint_as_float(rec.z));
            }
#pragma unroll
            for (int m = 32; m; m >>= 1) ll += __shfl_xor(ll, m, 64);
            wavesum = ll;
        }
    } else {
        const int tb = blockIdx.x - NB0;
        const int work1 = (tb & 7) * (NB1 / 8) + (tb >> 3);
        const long base = (long)(work1 * 4 + wv) * 64;
        if (base < NPAIRS) {
            const int g = lane >> 3, sub = lane & 7;
            long lpos = base + 8 * g + sub;
            if (lpos > NPAIRS - 1) lpos = NPAIRS - 1;
            const uint4 rec = srec[(size_t)NPAIRS + lpos];
            int prev_c = -1;
            float wc[24];
            float wb = 0.f, lg = 0.f;
#pragma unroll
            for (int j = 0; j < 8; ++j) {
                const bool valid = (base + 8 * g + j) < NPAIRS;  // group-uniform
                const int src = (lane & 56) | j;
                const int r = __shfl((int)rec.x, src, 64);
                const int c = __shfl((int)rec.y, src, 64);
                if (valid) {
                    if (c != prev_c) {
                        prev_c = c;
                        const unsigned char* wr = w18 + (size_t)c * 192 + 24 * sub;
                        uint2 wu0 = *(const uint2*)wr;
                        uint2 wu1 = *(const uint2*)(wr + 8);
                        uint2 wu2 = *(const uint2*)(wr + 16);
                        unpack8(wu0, &wc[0]);
                        unpack8(wu1, &wc[8]);
                        unpack8(wu2, &wc[16]);
                        wb = b1f[c];
                    }
                    const unsigned char* fr = feat8 + (size_t)r * FSIZE + COL1 + 24 * sub;
                    uint2 f0 = *(const uint2*)fr;
                    uint2 f1 = *(const uint2*)(fr + 8);
                    uint2 f2 = *(const uint2*)(fr + 16);
                    float s = dot8(f0, &wc[0], 0.f);
                    s = dot8(f1, &wc[8], s);
                    s = dot8(f2, &wc[16], s);
                    s += __shfl_xor(s, 4, 64);
                    s += __shfl_xor(s, 2, 64);
                    s += __shfl_xor(s, 1, 64);
                    lg = (sub == j) ? s * DESCALE + wb : lg;
                }
            }
            float ll = 0.f;
            if ((base + 8 * g + sub) < NPAIRS)
                ll = loss_term(lg, __uint_as_float(rec.z));
#pragma unroll
            for (int m = 32; m; m >>= 1) ll += __shfl_xor(ll, m, 64);
            wavesum = ll;
        }
    }

    if (lane == 0) bsum[wv] = wavesum;
    __syncthreads();
    if (threadIdx.x == 0)
        partial[blockIdx.x] = bsum[0] + bsum[1] + bsum[2] + bsum[3];
}

__global__ __launch_bounds__(1024) void reduce_kernel(
    const float* __restrict__ partial, int n, float* __restrict__ out)
{
    __shared__ float sh[1024];
    float s = 0.0f;
    for (int i = threadIdx.x; i < n; i += 1024) s += partial[i];
    sh[threadIdx.x] = s;
    __syncthreads();
    for (int off = 512; off; off >>= 1) {
        if ((int)threadIdx.x < off) sh[threadIdx.x] += sh[threadIdx.x + off];
        __syncthreads();
    }
    if (threadIdx.x == 0) out[0] = sh[0];
}

// ---------------- fallback (all-f32, unsorted, small ws) ----------------
__global__ __launch_bounds__(256) void task0_kernel(
    const float* __restrict__ feat, const float* __restrict__ wt,
    const int* __restrict__ idx, const float* __restrict__ y,
    float* __restrict__ out_final, float* __restrict__ partial)
{
    __shared__ float lsum[4];
    const int lane = threadIdx.x & 63;
    const int wv = threadIdx.x >> 6;
    const int pair = blockIdx.x * 4 + wv;
    const int r = idx[2 * pair];
    const int c = idx[2 * pair + 1];
    const float4* f4 = (const float4*)(feat + (size_t)r * FSIZE);
    const float* wrow = wt + (size_t)c * TW0;
    float s = 0.0f;
#pragma unroll
    for (int k = 0; k < 3; ++k) {
        const int j = lane + (k << 6);
        float4 f = f4[j];
        float4 w = ld4u(wrow + 4 * j);
        s += f.x * w.x + f.y * w.y + f.z * w.z + f.w * w.w;
    }
#pragma unroll
    for (int m = 32; m; m >>= 1) s += __shfl_xor(s, m, 64);
    if (lane == 0) {
        const float logit = s + wrow[FSIZE];
        out_final[pair] = logit;
        lsum[wv] = loss_term(logit, y[pair]);
    }
    __syncthreads();
    if (threadIdx.x == 0)
        partial[blockIdx.x] = lsum[0] + lsum[1] + lsum[2] + lsum[3];
}

__global__ __launch_bounds__(256) void task1_kernel(
    const float* __restrict__ feat, const float* __restrict__ wt,
    const int* __restrict__ idx, const float* __restrict__ y,
    float* __restrict__ partial)
{
    __shared__ float lsum[16];
    const int lane = threadIdx.x & 63;
    const int wv = threadIdx.x >> 6;
    const int sub = lane & 15;
    const int pg = lane >> 4;
    const int pair = (blockIdx.x * 4 + wv) * 4 + pg;
    const int r = idx[2 * pair];
    const int c = idx[2 * pair + 1];
    const float4* f4 = (const float4*)(feat + (size_t)r * FSIZE + COL1);
    const float* wrow = wt + (size_t)c * TW1;
    float s = 0.0f;
#pragma unroll
    for (int k = 0; k < 3; ++k) {
        const int j = sub + (k << 4);
        float4 f = f4[j];
        float4 w = ld4u(wrow + 4 * j);
        s += f.x * w.x + f.y * w.y + f.z * w.z + f.w * w.w;
    }
#pragma unroll
    for (int m = 8; m; m >>= 1) s += __shfl_xor(s, m, 64);
    if (sub == 0) {
        const float logit = s + wrow[TW1 - 1];
        lsum[wv * 4 + pg] = loss_term(logit, y[pair]);
    }
    __syncthreads();
    if (threadIdx.x == 0) {
        float t = 0.0f;
#pragma unroll
        for (int i = 0; i < 16; ++i) t += lsum[i];
        partial[blockIdx.x] = t;
    }
}

extern "C" void kernel_launch(void* const* d_in, const int* in_sizes, int n_in,
                              void* d_out, int out_size, void* d_ws, size_t ws_size,
                              hipStream_t stream) {
    const float* feat = (const float*)d_in[0];
    const float* w0   = (const float*)d_in[1];
    const float* w1   = (const float*)d_in[2];
    const int*   idx0 = (const int*)d_in[3];
    const float* y0   = (const float*)d_in[4];
    const int*   idx1 = (const int*)d_in[6];
    const float* y1   = (const float*)d_in[7];

    float* out = (float*)d_out;
    unsigned* ws = (unsigned*)d_ws;

    if (ws_size >= WS_U32 * 4) {
        unsigned char* feat8 = (unsigned char*)(ws + O_FEAT8);
        unsigned char* w08   = (unsigned char*)(ws + O_W08);
        unsigned char* w18   = (unsigned char*)(ws + O_W18);
        float* b0f   = (float*)(ws + O_B0F);
        float* b1f   = (float*)(ws + O_B1F);
        int*   cnt   = (int*)(ws + O_CNT);
        int*   cursor= (int*)(ws + O_CUR);
        uint4* srec  = (uint4*)(ws + O_SREC);
        float* part  = (float*)(ws + O_PART);

        zero_cnt_kernel<<<256, 256, 0, stream>>>(cnt);
        fused_pre_kernel<<<NPRE, 256, 0, stream>>>(
            feat, w0, w1, idx0, idx1,
            (uint2*)feat8, (uint2*)w08, (uint2*)w18, b0f, b1f, cnt);
        scan2_kernel<<<1, 1024, 0, stream>>>(cnt, cursor);
        scatter2_kernel<<<(2 * NPAIRS + 255) / 256, 256, 0, stream>>>(
            idx0, y0, idx1, y1, cursor, srec);
        main3_kernel<<<NGRID, 256, 0, stream>>>(
            feat8, w08, w18, b0f, b1f, srec, out, part);
        reduce_kernel<<<1, 1024, 0, stream>>>(part, NPART, out + NPAIRS);
    } else {
        float* part = (float*)ws;
        const int nb0 = NPAIRS / 4;
        const int nb1 = NPAIRS / 16;
        task0_kernel<<<nb0, 256, 0, stream>>>(feat, w0, idx0, y0, out, part);
        task1_kernel<<<nb1, 256, 0, stream>>>(feat, w1, idx1, y1, part + nb0);
        reduce_kernel<<<1, 1024, 0, stream>>>(part, nb0 + nb1, out + NPAIRS);
    }
}